// Round 1
// baseline (139.639 us; speedup 1.0000x reference)
//
#include <hip/hip_runtime.h>

#define N_NODES 8192
#define IN_F    1024
#define OUT_F   512
#define N_EDGES 262144
#define STRIDE  96                // fixed adjacency row stride; P(deg>=96) ~ 1e-18

// ---------------- workspace layout (bytes) ----------------
#define HID_OFF     0u            // 8192*512*2   =  8,388,608  (bf16 H)
#define XB_OFF      8388608u      // 8192*1024*2  = 16,777,216  (bf16 X)
#define WB_OFF      25165824u     // 512*1024*2   =  1,048,576  (bf16 W, contiguous after Xb)
#define DEG_OFF     26214400u     // 8192*4 = 32,768
#define COL_OFF     26247168u     // 8192*96*4 = 3,145,728 -> ends 29,392,896
#define MAX_DEG     STRIDE

typedef short  bf16x8 __attribute__((ext_vector_type(8)));
typedef float  f32x4  __attribute__((ext_vector_type(4)));

__device__ __forceinline__ unsigned short f2bf(float f) {
    unsigned u = __float_as_uint(f);
    u += 0x7fffu + ((u >> 16) & 1u);   // round-to-nearest-even
    return (unsigned short)(u >> 16);
}

__device__ __forceinline__ float bflo(unsigned u) { return __uint_as_float(u << 16); }
__device__ __forceinline__ float bfhi(unsigned u) { return __uint_as_float(u & 0xffff0000u); }

__device__ __forceinline__ void ld_lds16(const void* g, void* l) {
    __builtin_amdgcn_global_load_lds(
        (const __attribute__((address_space(1))) void*)g,
        (__attribute__((address_space(3))) void*)l, 16, 0, 0);
}

// --- fp32 -> bf16 for X and W in one launch; first 8192 threads zero deg ---
#define NX8 (N_NODES * IN_F / 8)          // 1,048,576 chunks of 8
#define NW8 (OUT_F * IN_F / 8)            //    65,536
__global__ __launch_bounds__(256) void cvt_bf16_all(const float* __restrict__ x,
                                                    const float* __restrict__ w,
                                                    unsigned short* __restrict__ xb,
                                                    int* __restrict__ deg) {
    int i = blockIdx.x * blockDim.x + threadIdx.x;
    if (i < N_NODES) deg[i] = 0;
    if (i >= NX8 + NW8) return;
    const f32x4* p = (i < NX8) ? ((const f32x4*)x + (size_t)i * 2)
                               : ((const f32x4*)w + (size_t)(i - NX8) * 2);
    f32x4 v0 = __builtin_nontemporal_load(p);      // x/w not re-read as fp32
    f32x4 v1 = __builtin_nontemporal_load(p + 1);
    uint4 o;
    o.x = (unsigned)f2bf(v0.x) | ((unsigned)f2bf(v0.y) << 16);
    o.y = (unsigned)f2bf(v0.z) | ((unsigned)f2bf(v0.w) << 16);
    o.z = (unsigned)f2bf(v1.x) | ((unsigned)f2bf(v1.y) << 16);
    o.w = (unsigned)f2bf(v1.z) | ((unsigned)f2bf(v1.w) << 16);
    *((uint4*)xb + i) = o;
}

// ------- fused: MFMA GEMM (blocks 0..511) + edge scatter (512..1535) -----
// GEMM: 128x64 tile, BK=64 (16 iters), 4 waves (2m x 2n), wave = 64x32 out
// (4x2 frags of 16x16, acc 32 VGPR).  Double-buffered LDS, ONE barrier per
// K-step: stage tile t+1 into buf^1, compute tile t from buf, sync (drains
// the in-flight global_load_lds), flip.  LDS XOR-swizzle as before: logical
// chunk (row,kq) lives at slot row*8+(kq^(row&7)); global_load_lds forces
// slot=lane, so the swizzle is applied by permuting the GLOBAL chunk each
// lane fetches (permutation stays within 128 B -> coalescing preserved).
#define GEMM_BLOCKS 512

__global__ __launch_bounds__(256, 2) void gemm_scatter(const unsigned short* __restrict__ Xb,
                                                       const unsigned short* __restrict__ Wb,
                                                       const float* __restrict__ bias,
                                                       unsigned short* __restrict__ H,
                                                       const int* __restrict__ src,
                                                       const int* __restrict__ dst,
                                                       int* __restrict__ deg,
                                                       int* __restrict__ col) {
    __shared__ unsigned short As[2][128 * 64];   // 32 KB
    __shared__ unsigned short Bs[2][64 * 64];    // 16 KB

    const int bid = blockIdx.x;
    const int tid = threadIdx.x;

    if (bid >= GEMM_BLOCKS) {                 // ---- scatter part ----
        int e = (bid - GEMM_BLOCKS) * 256 + tid;   // 1024*256 == N_EDGES exactly
        int s = src[e];
        int slot = atomicAdd(&deg[s], 1);
        if (slot < STRIDE) col[s * STRIDE + slot] = dst[e];
        return;
    }

    // ---- GEMM part ----
    const int lane = tid & 63;
    const int wave = tid >> 6;
    const int row0 = (bid & 63) * 128;        // 64 row-tiles; bids r+64c share XCD -> A L2-resident
    const int col0 = (bid >> 6) * 64;         // 8 col-tiles
    const int wm   = (wave & 1) * 64;
    const int wn   = (wave >> 1) * 32;
    const int fm   = lane & 15;
    const int fm7  = fm & 7;
    const int q    = lane >> 4;               // k-quad within the 32-k MFMA window

    f32x4 acc[4][2];
#pragma unroll
    for (int i = 0; i < 4; ++i)
#pragma unroll
        for (int j = 0; j < 2; ++j) acc[i][j] = (f32x4)0.f;

    // staging: slot = tid covers (r = tid>>3, swizzled k-chunk); +256 -> r+32, ...
    const int r0 = tid >> 3;                              // 0..31
    const int kp = ((tid & 7) ^ (r0 & 7)) * 8;            // swizzled k elem-offset
    const unsigned short* Xbase = Xb + (size_t)(row0 + r0) * IN_F + kp;
    const unsigned short* Wbase = Wb + (size_t)(col0 + r0) * IN_F + kp;

#define STAGE(buf, k0) do {                                                   \
    ld_lds16(Xbase            + (k0), &As[buf][tid * 8]);                     \
    ld_lds16(Xbase + 32*IN_F  + (k0), &As[buf][(tid + 256) * 8]);             \
    ld_lds16(Xbase + 64*IN_F  + (k0), &As[buf][(tid + 512) * 8]);             \
    ld_lds16(Xbase + 96*IN_F  + (k0), &As[buf][(tid + 768) * 8]);             \
    ld_lds16(Wbase            + (k0), &Bs[buf][tid * 8]);                     \
    ld_lds16(Wbase + 32*IN_F  + (k0), &Bs[buf][(tid + 256) * 8]);             \
} while (0)

#define COMPUTE(buf) do {                                                     \
    _Pragma("unroll")                                                         \
    for (int s = 0; s < 2; ++s) {                                             \
        const int kq = s * 4 + q;                                             \
        bf16x8 a[4], b[2];                                                    \
        _Pragma("unroll")                                                     \
        for (int mi = 0; mi < 4; ++mi)                                        \
            a[mi] = *(const bf16x8*)&As[buf][(((wm + mi*16 + fm) << 3) + (kq ^ fm7)) << 3]; \
        _Pragma("unroll")                                                     \
        for (int ni = 0; ni < 2; ++ni)                                        \
            b[ni] = *(const bf16x8*)&Bs[buf][(((wn + ni*16 + fm) << 3) + (kq ^ fm7)) << 3]; \
        _Pragma("unroll")                                                     \
        for (int mi = 0; mi < 4; ++mi)                                        \
            _Pragma("unroll")                                                 \
            for (int ni = 0; ni < 2; ++ni)                                    \
                acc[mi][ni] = __builtin_amdgcn_mfma_f32_16x16x32_bf16(        \
                    a[mi], b[ni], acc[mi][ni], 0, 0, 0);                      \
    }                                                                         \
} while (0)

    STAGE(0, 0);
    __syncthreads();                          // drain prologue stage
    int cur = 0;
    for (int t = 0; t < 15; ++t) {
        STAGE(cur ^ 1, (t + 1) * 64);         // prefetch next K-tile (other buffer)
        COMPUTE(cur);                         // MFMA on current tile overlaps the loads
        __syncthreads();                      // one barrier/K-step: drains vmcnt + sync
        cur ^= 1;
    }
    COMPUTE(cur);                             // last tile, nothing left to stage

    const int cm = (lane >> 4) * 4;   // C/D: col = lane&15, row = (lane>>4)*4 + reg
#pragma unroll
    for (int ni = 0; ni < 2; ++ni) {
        const int c = col0 + wn + ni * 16 + fm;
        const float bv = bias[c];
#pragma unroll
        for (int mi = 0; mi < 4; ++mi) {
#pragma unroll
            for (int r = 0; r < 4; ++r) {
                const int row = row0 + wm + mi * 16 + cm + r;
                H[(size_t)row * OUT_F + c] = f2bf(acc[mi][ni][r] + bv);
            }
        }
    }
#undef STAGE
#undef COMPUTE
}

// ---- aggregate: wave-per-node. 64 lanes x 8 feats = 512. No block barriers. ----
__global__ __launch_bounds__(256) void aggregate(const unsigned short* __restrict__ H,
                                                 const int* __restrict__ dg,
                                                 const int* __restrict__ col,
                                                 float* __restrict__ out) {
    __shared__ int nbr[4][MAX_DEG];
    __shared__ int uniq[4][MAX_DEG];
    __shared__ int wcnt[4];
    const int wave = threadIdx.x >> 6;
    const int lane = threadIdx.x & 63;
    const int v    = blockIdx.x * 4 + wave;
    int d = dg[v];
    if (d > MAX_DEG) d = MAX_DEG;

    if (lane == 0) wcnt[wave] = 0;
    int id0 = -1, id1 = -1;
    if (lane < d)      { id0 = col[v * STRIDE + lane];      nbr[wave][lane]      = id0; }
    if (64 + lane < d) { id1 = col[v * STRIDE + 64 + lane]; nbr[wave][64 + lane] = id1; }
    __builtin_amdgcn_wave_barrier();   // wave-synchronous; pin scheduling across LDS use

    // keep entry i iff no j<i equals it (no early exit -> LDS reads pipeline)
    bool k0 = (lane < d);
    const int lim0 = k0 ? lane : 0;
    for (int j = 0; j < lim0; ++j) k0 = k0 & (nbr[wave][j] != id0);
    bool k1 = (64 + lane < d);
    const int lim1 = k1 ? (64 + lane) : 0;
    for (int j = 0; j < lim1; ++j) k1 = k1 & (nbr[wave][j] != id1);
    if (k0) uniq[wave][atomicAdd(&wcnt[wave], 1)] = id0;
    if (k1) uniq[wave][atomicAdd(&wcnt[wave], 1)] = id1;
    __builtin_amdgcn_wave_barrier();
    const int n  = wcnt[wave];
    const int f0 = lane * 8;              // lane covers 8 feats (uint4 = 8 bf16)

    float a0=0,a1=0,a2=0,a3=0,a4=0,a5=0,a6=0,a7=0;
    int e = 0;
    for (; e + 8 <= n; e += 8) {          // 8 rows in flight per iteration (MLP)
        const int i0 = uniq[wave][e],   i1 = uniq[wave][e+1],
                  i2 = uniq[wave][e+2], i3 = uniq[wave][e+3],
                  i4 = uniq[wave][e+4], i5 = uniq[wave][e+5],
                  i6 = uniq[wave][e+6], i7 = uniq[wave][e+7];
        uint4 h0 = *(const uint4*)&H[(size_t)i0 * OUT_F + f0];
        uint4 h1 = *(const uint4*)&H[(size_t)i1 * OUT_F + f0];
        uint4 h2 = *(const uint4*)&H[(size_t)i2 * OUT_F + f0];
        uint4 h3 = *(const uint4*)&H[(size_t)i3 * OUT_F + f0];
        uint4 h4 = *(const uint4*)&H[(size_t)i4 * OUT_F + f0];
        uint4 h5 = *(const uint4*)&H[(size_t)i5 * OUT_F + f0];
        uint4 h6 = *(const uint4*)&H[(size_t)i6 * OUT_F + f0];
        uint4 h7 = *(const uint4*)&H[(size_t)i7 * OUT_F + f0];
        a0 += (bflo(h0.x)+bflo(h1.x)) + (bflo(h2.x)+bflo(h3.x))
            + (bflo(h4.x)+bflo(h5.x)) + (bflo(h6.x)+bflo(h7.x));
        a1 += (bfhi(h0.x)+bfhi(h1.x)) + (bfhi(h2.x)+bfhi(h3.x))
            + (bfhi(h4.x)+bfhi(h5.x)) + (bfhi(h6.x)+bfhi(h7.x));
        a2 += (bflo(h0.y)+bflo(h1.y)) + (bflo(h2.y)+bflo(h3.y))
            + (bflo(h4.y)+bflo(h5.y)) + (bflo(h6.y)+bflo(h7.y));
        a3 += (bfhi(h0.y)+bfhi(h1.y)) + (bfhi(h2.y)+bfhi(h3.y))
            + (bfhi(h4.y)+bfhi(h5.y)) + (bfhi(h6.y)+bfhi(h7.y));
        a4 += (bflo(h0.z)+bflo(h1.z)) + (bflo(h2.z)+bflo(h3.z))
            + (bflo(h4.z)+bflo(h5.z)) + (bflo(h6.z)+bflo(h7.z));
        a5 += (bfhi(h0.z)+bfhi(h1.z)) + (bfhi(h2.z)+bfhi(h3.z))
            + (bfhi(h4.z)+bfhi(h5.z)) + (bfhi(h6.z)+bfhi(h7.z));
        a6 += (bflo(h0.w)+bflo(h1.w)) + (bflo(h2.w)+bflo(h3.w))
            + (bflo(h4.w)+bflo(h5.w)) + (bflo(h6.w)+bflo(h7.w));
        a7 += (bfhi(h0.w)+bfhi(h1.w)) + (bfhi(h2.w)+bfhi(h3.w))
            + (bfhi(h4.w)+bfhi(h5.w)) + (bfhi(h6.w)+bfhi(h7.w));
    }
    for (; e + 4 <= n; e += 4) {
        const int i0 = uniq[wave][e], i1 = uniq[wave][e+1],
                  i2 = uniq[wave][e+2], i3 = uniq[wave][e+3];
        uint4 h0 = *(const uint4*)&H[(size_t)i0 * OUT_F + f0];
        uint4 h1 = *(const uint4*)&H[(size_t)i1 * OUT_F + f0];
        uint4 h2 = *(const uint4*)&H[(size_t)i2 * OUT_F + f0];
        uint4 h3 = *(const uint4*)&H[(size_t)i3 * OUT_F + f0];
        a0 += bflo(h0.x)+bflo(h1.x)+bflo(h2.x)+bflo(h3.x);
        a1 += bfhi(h0.x)+bfhi(h1.x)+bfhi(h2.x)+bfhi(h3.x);
        a2 += bflo(h0.y)+bflo(h1.y)+bflo(h2.y)+bflo(h3.y);
        a3 += bfhi(h0.y)+bfhi(h1.y)+bfhi(h2.y)+bfhi(h3.y);
        a4 += bflo(h0.z)+bflo(h1.z)+bflo(h2.z)+bflo(h3.z);
        a5 += bfhi(h0.z)+bfhi(h1.z)+bfhi(h2.z)+bfhi(h3.z);
        a6 += bflo(h0.w)+bflo(h1.w)+bflo(h2.w)+bflo(h3.w);
        a7 += bfhi(h0.w)+bfhi(h1.w)+bfhi(h2.w)+bfhi(h3.w);
    }
    for (; e < n; ++e) {
        uint4 h0 = *(const uint4*)&H[(size_t)uniq[wave][e] * OUT_F + f0];
        a0 += bflo(h0.x); a1 += bfhi(h0.x);
        a2 += bflo(h0.y); a3 += bfhi(h0.y);
        a4 += bflo(h0.z); a5 += bfhi(h0.z);
        a6 += bflo(h0.w); a7 += bfhi(h0.w);
    }
    f32x4 o0 = {fmaxf(a0,0.f), fmaxf(a1,0.f), fmaxf(a2,0.f), fmaxf(a3,0.f)};
    f32x4 o1 = {fmaxf(a4,0.f), fmaxf(a5,0.f), fmaxf(a6,0.f), fmaxf(a7,0.f)};
    // out is never re-read -> nontemporal, keep L2 for the H gather table
    __builtin_nontemporal_store(o0, (f32x4*)&out[(size_t)v * OUT_F + f0]);
    __builtin_nontemporal_store(o1, (f32x4*)&out[(size_t)v * OUT_F + f0 + 4]);
}

extern "C" void kernel_launch(void* const* d_in, const int* in_sizes, int n_in,
                              void* d_out, int out_size, void* d_ws, size_t ws_size,
                              hipStream_t stream) {
    const float* x  = (const float*)d_in[0];
    const float* W  = (const float*)d_in[1];
    const float* b  = (const float*)d_in[2];
    const int*   ei = (const int*)d_in[3];      // [2, N_EDGES]: src then dst
    float* out = (float*)d_out;

    char* ws = (char*)d_ws;
    unsigned short* H   = (unsigned short*)(ws + HID_OFF);
    unsigned short* Xb  = (unsigned short*)(ws + XB_OFF);   // Wb contiguous after
    unsigned short* Wb  = (unsigned short*)(ws + WB_OFF);
    int*            deg = (int*)(ws + DEG_OFF);
    int*            col = (int*)(ws + COL_OFF);

    // 1) convert X,W to bf16 + zero deg
    cvt_bf16_all<<<(NX8 + NW8 + 255) / 256, 256, 0, stream>>>(x, W, Xb, deg);

    // 2) GEMM (512 blocks, 128x64 tile, dbuf) + edge scatter (1024 blocks) fused
    gemm_scatter<<<GEMM_BLOCKS + N_EDGES / 256, 256, 0, stream>>>(Xb, Wb, b, H, ei, ei + N_EDGES, deg, col);

    // 3) per-node dedup + gather + ReLU, one wave per node
    aggregate<<<N_NODES / 4, 256, 0, stream>>>(H, deg, col, out);
}